// Round 1
// baseline (594.785 us; speedup 1.0000x reference)
//
#include <hip/hip_runtime.h>

// EM routing (matrix capsules), B=16,H=6,W=6,KH=KW=3,I=32,O=32,A=4, ITERATIONS=2.
// One workgroup per spatial site (b,h,w): 576 sites.
// Pass 1: M-step-1 moments (direct coalesced read of the 576KB site tile).
// Pass 2: per input-capsule i, stage the (kk,o,a2) slice (18KB) in LDS once,
//         compute lognum -> logsumexp over (kk,o) -> R2, and accumulate the
//         R2*act*0.8 weighted moments. The 0.2*R_prev part of M-step-2 is
//         algebraically 0.2 * (M-step-1 sums) -> free.
// Votes traffic: exactly 2 full reads (structural minimum for this dep chain).

#define KKc 9
#define NIc 32
#define NOc 32
#define NAc 16
#define KIc 288   // KKc*NIc
#define KOc 288   // KKc*NOc
#define NPc 512   // NOc*NAc
#define MSTR 17   // padded stride for [o][a2] arrays (bank-conflict-free)

__device__ __forceinline__ float wave_sum(float v) {
#pragma unroll
  for (int off = 32; off; off >>= 1) v += __shfl_down(v, off, 64);
  return v;
}
__device__ __forceinline__ float wave_max(float v) {
#pragma unroll
  for (int off = 32; off; off >>= 1) v = fmaxf(v, __shfl_down(v, off, 64));
  return v;
}

__global__ __launch_bounds__(256, 4)
void em_routing_kernel(const float* __restrict__ votes,
                       const float* __restrict__ acts_in,
                       const float* __restrict__ beta_a,
                       const float* __restrict__ beta_u,
                       float* __restrict__ out, int nsite)
{
  const int site = blockIdx.x;
  const int t    = threadIdx.x;
  const float EPSf  = 1e-7f;
  const float TWO_PI = 6.28318530717958647692f;

  __shared__ float s_VT[NAc * KOc];   // transposed slice: [a2][kk*32+o]
  __shared__ float s_act[KIc];        // [kk*32+i]
  __shared__ float s_mu1[NOc * MSTR];
  __shared__ float s_lt1[NOc * MSTR]; // log(2*pi*sig1+EPS)
  __shared__ float s_i2s[NOc * MSTR]; // 0.5/sig1
  __shared__ float s_m1v[NOc * MSTR]; // sum R1*V
  __shared__ float s_m1q[NOc * MSTR]; // sum R1*V^2
  __shared__ float s_laj[NOc];        // log(a_j1+EPS)
  __shared__ float s_ln[KOc];         // lognum for current i
  __shared__ float s_w[KOc];          // R2*act*0.8 for current i
  __shared__ float s_sR2[NOc];
  __shared__ float s_red[4];
  __shared__ float s_red2[256];

  const float* vsite = votes + (size_t)site * (KIc * NPc);

  // ---- load activations for this site ----
  s_act[t] = acts_in[site * KIc + t];
  if (t < KIc - 256) s_act[t + 256] = acts_in[site * KIc + t + 256];
  __syncthreads();

  // ---- sumR1 = sum_ki (0.8*act+0.2)/32  (o-independent) ----
  float sumR1;
  {
    float v = fmaf(0.8f, s_act[t], 0.2f);
    if (t < KIc - 256) v += fmaf(0.8f, s_act[t + 256], 0.2f);
    v = wave_sum(v);
    if ((t & 63) == 0) s_red[t >> 6] = v;
    __syncthreads();
    sumR1 = (s_red[0] + s_red[1] + s_red[2] + s_red[3]) * 0.03125f;
    __syncthreads();
  }

  // ---- Pass 1: M-step-1 moments. Thread owns pairs p=2t,2t+1 (coalesced float2) ----
  float p1v0 = 0.f, p1v1 = 0.f, p1q0 = 0.f, p1q1 = 0.f;
#pragma unroll 4
  for (int ki = 0; ki < KIc; ++ki) {
    const float r = fmaf(0.8f, s_act[ki], 0.2f) * 0.03125f;
    const float2 v = *reinterpret_cast<const float2*>(vsite + ki * NPc + 2 * t);
    p1v0 = fmaf(r, v.x, p1v0);
    p1q0 = fmaf(r, v.x * v.x, p1q0);
    p1v1 = fmaf(r, v.y, p1v1);
    p1q1 = fmaf(r, v.y * v.y, p1q1);
  }
  {
    const int o1  = t >> 3;         // p=2t -> o = p/16
    const int a2a = (t & 7) * 2;
    const float sR1e = sumR1 + EPSf;
    const float mua = p1v0 / sR1e;
    const float mub = p1v1 / sR1e;
    // sum R(V-mu)^2 = sum RV^2 - mu^2*(sumR + 2*EPS)
    const float sga = fmaxf((p1q0 - mua * mua * (sumR1 + 2.f * EPSf)) / sR1e, 0.f);
    const float sgb = fmaxf((p1q1 - mub * mub * (sumR1 + 2.f * EPSf)) / sR1e, 0.f);
    const int b = o1 * MSTR + a2a;
    s_mu1[b]     = mua;  s_mu1[b + 1] = mub;
    s_lt1[b]     = logf(TWO_PI * sga + EPSf);
    s_lt1[b + 1] = logf(TWO_PI * sgb + EPSf);
    s_i2s[b]     = 0.5f / sga;
    s_i2s[b + 1] = 0.5f / sgb;
    s_m1v[b] = p1v0; s_m1v[b + 1] = p1v1;
    s_m1q[b] = p1q0; s_m1q[b + 1] = p1q1;
    const float bu = beta_u[o1];
    float ch = (bu - 0.5f * logf(sga + EPSf)) * sumR1
             + (bu - 0.5f * logf(sgb + EPSf)) * sumR1;
#pragma unroll
    for (int off = 1; off < 8; off <<= 1) ch += __shfl_xor(ch, off, 64);
    if ((t & 7) == 0) {
      // inv_temp (it=0) = 0.01*(1-0.95) = 0.0005
      const float aj = 1.f / (1.f + expf(-(0.0005f * (beta_a[o1] - ch))));
      s_laj[o1] = logf(aj + EPSf);
    }
  }
  __syncthreads();

  // ---- Pass 2: per-i E-step + M-step-2 weighted moments ----
  float sR2acc = 0.f;                       // valid for t<32 (o = t)
  float m2va = 0.f, m2vb = 0.f, m2qa = 0.f, m2qb = 0.f;
  const int oB  = t & 31;                   // accumulation mapping (conflict-free)
  const int a2B = (t >> 5) * 2;

  for (int i = 0; i < NIc; ++i) {
    __syncthreads();  // protect s_VT/s_ln/s_w from previous-iter readers
    // stage the i-slice transposed: s_VT[a2][kk*32+o]
    for (int idx = t; idx < KKc * 128; idx += 256) {
      const int kk  = idx >> 7;
      const int rem = idx & 127;
      const int o   = rem >> 2;
      const int a4  = (rem & 3) * 4;
      const float4 v = reinterpret_cast<const float4*>(vsite)[(kk * NIc + i) * 128 + rem];
      s_VT[(a4 + 0) * KOc + kk * NOc + o] = v.x;
      s_VT[(a4 + 1) * KOc + kk * NOc + o] = v.y;
      s_VT[(a4 + 2) * KOc + kk * NOc + o] = v.z;
      s_VT[(a4 + 3) * KOc + kk * NOc + o] = v.w;
    }
    __syncthreads();

    // lognum(kk,o) = log(a_j1[o]+EPS) - sum_a2 [log(2pi*sig+EPS) + (V-mu)^2/(2 sig)]
    float ln1, ln2 = -1e30f;
    {
      const int o  = t & 31;
      const int ob = o * MSTR;
      float lp = 0.f;
#pragma unroll
      for (int a2 = 0; a2 < NAc; ++a2) {
        const float d = s_VT[a2 * KOc + t] - s_mu1[ob + a2];
        lp += s_lt1[ob + a2] + d * d * s_i2s[ob + a2];
      }
      ln1 = s_laj[o] - lp;
      s_ln[t] = ln1;
    }
    if (t < KOc - 256) {
      const int idx = t + 256;
      const int o   = idx & 31;
      const int ob  = o * MSTR;
      float lp = 0.f;
#pragma unroll
      for (int a2 = 0; a2 < NAc; ++a2) {
        const float d = s_VT[a2 * KOc + idx] - s_mu1[ob + a2];
        lp += s_lt1[ob + a2] + d * d * s_i2s[ob + a2];
      }
      ln2 = s_laj[o] - lp;
      s_ln[idx] = ln2;
    }
    // logsumexp over the 288 (kk,o) values
    float m = wave_max(fmaxf(ln1, ln2));
    if ((t & 63) == 0) s_red[t >> 6] = m;
    __syncthreads();
    m = fmaxf(fmaxf(s_red[0], s_red[1]), fmaxf(s_red[2], s_red[3]));
    float e = expf(ln1 - m) + ((t < KOc - 256) ? expf(ln2 - m) : 0.f);
    e = wave_sum(e);
    __syncthreads();
    if ((t & 63) == 0) s_red[t >> 6] = e;
    __syncthreads();
    const float logden = m + logf(s_red[0] + s_red[1] + s_red[2] + s_red[3]);

    // w = R2 * act * 0.8
    {
      const int kk = t >> 5;
      s_w[t] = expf(ln1 - logden) * s_act[kk * NIc + i] * 0.8f;
    }
    if (t < KOc - 256) {
      const int idx = t + 256;
      const int kk  = idx >> 5;
      s_w[idx] = expf(ln2 - logden) * s_act[kk * NIc + i] * 0.8f;
    }
    __syncthreads();

    if (t < NOc) {
      float sw = 0.f;
#pragma unroll
      for (int kk = 0; kk < KKc; ++kk) sw += s_w[kk * NOc + t];
      sR2acc += sw;
    }
#pragma unroll
    for (int kk = 0; kk < KKc; ++kk) {
      const int bb = kk * NOc + oB;
      const float w  = s_w[bb];
      const float va = s_VT[a2B * KOc + bb];
      const float vb = s_VT[(a2B + 1) * KOc + bb];
      m2va = fmaf(w, va, m2va);
      m2qa = fmaf(w, va * va, m2qa);
      m2vb = fmaf(w, vb, m2vb);
      m2qb = fmaf(w, vb * vb, m2qb);
    }
  }

  if (t < NOc) s_sR2[t] = sR2acc;
  __syncthreads();

  // ---- Finalize M-step-2 and write outputs ----
  {
    const float sumR = s_sR2[oB] + 0.2f * sumR1;
    const float sRe  = sumR + EPSf;
    const int b = oB * MSTR + a2B;
    const float Mva = m2va + 0.2f * s_m1v[b];
    const float Mqa = m2qa + 0.2f * s_m1q[b];
    const float Mvb = m2vb + 0.2f * s_m1v[b + 1];
    const float Mqb = m2qb + 0.2f * s_m1q[b + 1];
    const float mua = Mva / sRe;
    const float mub = Mvb / sRe;
    const float sga = fmaxf((Mqa - mua * mua * (sumR + 2.f * EPSf)) / sRe, 0.f);
    const float sgb = fmaxf((Mqb - mub * mub * (sumR + 2.f * EPSf)) / sRe, 0.f);

    float* poses = out + (size_t)site * NPc;
    poses[oB * NAc + a2B]     = mua;
    poses[oB * NAc + a2B + 1] = mub;

    const float bu = beta_u[oB];
    const float ch = (bu - 0.5f * logf(sga + EPSf)) * sumR
                   + (bu - 0.5f * logf(sgb + EPSf)) * sumR;
    s_red2[t] = ch;
  }
  __syncthreads();
  if (t < NOc) {
    float c = 0.f;
#pragma unroll
    for (int k = 0; k < 8; ++k) c += s_red2[t + 32 * k];
    // inv_temp (it_idx=ITERATIONS=2) = 0.01*(1-0.95^3) = 0.00142625
    const float aj = 1.f / (1.f + expf(-(0.00142625f * (beta_a[t] - c))));
    out[(size_t)nsite * NPc + site * NOc + t] = aj;
  }
}

extern "C" void kernel_launch(void* const* d_in, const int* in_sizes, int n_in,
                              void* d_out, int out_size, void* d_ws, size_t ws_size,
                              hipStream_t stream) {
  const float* votes  = (const float*)d_in[0];
  const float* acts   = (const float*)d_in[1];
  const float* beta_a = (const float*)d_in[2];
  const float* beta_u = (const float*)d_in[3];
  float* out = (float*)d_out;
  const int nsite = 16 * 6 * 6;  // B*H*W = 576
  em_routing_kernel<<<nsite, 256, 0, stream>>>(votes, acts, beta_a, beta_u, out, nsite);
}

// Round 2
// 562.186 us; speedup vs baseline: 1.0580x; 1.0580x over previous
//
#include <hip/hip_runtime.h>

// EM routing (matrix capsules), B=16,H=6,W=6,KH=KW=3,I=32,O=32,A=4, ITERATIONS=2.
//
// R2 restructure: R1's single 576-block kernel was latency-bound (VALUBusy 14%,
// HBM 15%, occupancy 24%) — 2.25 blocks/CU serialized by ~190 barriers each.
// Split into 3 streaming kernels with big grids:
//   K1: (site, p-quarter) blocks  -> M-step-1 moments + mu1/i2s/base tables.
//       Pure coalesced reduction over ki=288, no barriers in the hot loop.
//   K3: (site, 4-i group) blocks  -> E-step + M-step-2 weighted moments,
//       per-block partials to ws. 4608 blocks -> barrier stalls overlap.
//   K4: per-site finalize: sum partials, 0.2*M1 mix, mu2/sig2/a_j2, outputs.
// Votes read exactly twice (K1 + K3) = structural minimum. Target: BW-bound.

#define KKc 9
#define NIc 32
#define NOc 32
#define NAc 16
#define KIc 288    // KKc*NIc
#define KOc 288    // KKc*NOc
#define NPc 512    // NOc*NAc
#define NSITE 576
#define VSTR 17    // padded LDS stride for [pair][a2] / [o][a2] arrays

#define EPSf 1e-7f
#define TWO_PIf 6.28318530717958647692f

__device__ __forceinline__ float wave_sum(float v) {
#pragma unroll
  for (int off = 32; off; off >>= 1) v += __shfl_down(v, off, 64);
  return v;
}
__device__ __forceinline__ float wave_max(float v) {
#pragma unroll
  for (int off = 32; off; off >>= 1) v = fmaxf(v, __shfl_down(v, off, 64));
  return v;
}

// ---------------- K1: M-step-1 ----------------
// grid 2304 = site*4 + quarter; block 128. Thread owns p = quarter*128 + t.
__global__ __launch_bounds__(128)
void em_k1(const float* __restrict__ votes, const float* __restrict__ acts_in,
           const float* __restrict__ beta_a, const float* __restrict__ beta_u,
           float* __restrict__ w_mu1, float* __restrict__ w_i2s,
           float* __restrict__ w_m1v, float* __restrict__ w_m1q,
           float* __restrict__ w_base, float* __restrict__ w_sR1)
{
  const int site = blockIdx.x >> 2;
  const int qtr  = blockIdx.x & 3;
  const int t    = threadIdx.x;
  const int p    = qtr * 128 + t;

  __shared__ float s_act[KIc];
  __shared__ float s_red[2];

  s_act[t] = acts_in[site * KIc + t];
  s_act[t + 128] = acts_in[site * KIc + t + 128];
  if (t < 32) s_act[t + 256] = acts_in[site * KIc + t + 256];
  __syncthreads();

  // sumR1 = sum_ki (0.8*act+0.2)/32
  float v = fmaf(0.8f, s_act[t], 0.2f) + fmaf(0.8f, s_act[t + 128], 0.2f);
  if (t < 32) v += fmaf(0.8f, s_act[t + 256], 0.2f);
  v = wave_sum(v);
  if ((t & 63) == 0) s_red[t >> 6] = v;
  __syncthreads();
  const float sumR1 = (s_red[0] + s_red[1]) * 0.03125f;

  // streaming moment reduction: pv = sum r*V, pq = sum r*V^2
  float pv = 0.f, pq = 0.f;
  const float* vs = votes + (size_t)site * (KIc * NPc) + p;
#pragma unroll 8
  for (int ki = 0; ki < KIc; ++ki) {
    const float r = fmaf(0.8f, s_act[ki], 0.2f) * 0.03125f;
    const float x = vs[(size_t)ki * NPc];
    pv = fmaf(r, x, pv);
    pq = fmaf(r, x * x, pq);
  }

  const int o = p >> 4;
  const float sR1e = sumR1 + EPSf;
  const float mu = pv / sR1e;
  const float sg = fmaxf((pq - mu * mu * (sumR1 + 2.f * EPSf)) / sR1e, 0.f);

  w_mu1[(size_t)site * NPc + p] = mu;
  w_i2s[(size_t)site * NPc + p] = 0.5f / sg;
  w_m1v[(size_t)site * NPc + p] = pv;
  w_m1q[(size_t)site * NPc + p] = pq;

  float lt = logf(TWO_PIf * sg + EPSf);
  float ch = (beta_u[o] - 0.5f * logf(sg + EPSf)) * sumR1;
#pragma unroll
  for (int off = 1; off < 16; off <<= 1) {
    ch += __shfl_xor(ch, off, 64);
    lt += __shfl_xor(lt, off, 64);
  }
  if ((t & 15) == 0) {
    // inv_temp (it=0) = 0.01*(1-0.95) = 0.0005
    const float aj = 1.f / (1.f + expf(-(0.0005f * (beta_a[o] - ch))));
    w_base[site * NOc + o] = logf(aj + EPSf) - lt;  // log a_j1 - sum lt1 terms
  }
  if (t == 0) w_sR1[site] = sumR1;  // all 4 quarter-blocks write identical value
}

// ---------------- K3: E-step + M-step-2 partials ----------------
// grid 4608 = site*8 + igroup; block 256; igroup covers i = ig*4 .. ig*4+3.
__global__ __launch_bounds__(256)
void em_k3(const float* __restrict__ votes, const float* __restrict__ acts_in,
           const float* __restrict__ w_mu1, const float* __restrict__ w_i2s,
           const float* __restrict__ w_base,
           float* __restrict__ w_m2v, float* __restrict__ w_m2q,
           float* __restrict__ w_sR2)
{
  const int site = blockIdx.x >> 3;
  const int ig   = blockIdx.x & 7;
  const int t    = threadIdx.x;

  __shared__ float s_V[KOc * VSTR];    // [pair=kk*32+o][a2], stride 17
  __shared__ float s_mu[NOc * VSTR];
  __shared__ float s_is[NOc * VSTR];
  __shared__ float s_base[NOc];
  __shared__ float s_act[KIc];
  __shared__ float s_w[KOc];
  __shared__ float s_red[4];

  // tables
  for (int idx = t; idx < NPc; idx += 256) {
    const int o = idx >> 4, a2 = idx & 15;
    s_mu[o * VSTR + a2] = w_mu1[(size_t)site * NPc + idx];
    s_is[o * VSTR + a2] = w_i2s[(size_t)site * NPc + idx];
  }
  if (t < NOc) s_base[t] = w_base[site * NOc + t];
  s_act[t] = acts_in[site * KIc + t];
  if (t < KIc - 256) s_act[t + 256] = acts_in[site * KIc + t + 256];

  const float4* vsite4 = reinterpret_cast<const float4*>(votes + (size_t)site * (KIc * NPc));

  float m2va = 0.f, m2vb = 0.f, m2qa = 0.f, m2qb = 0.f, sR2acc = 0.f;
  const int oB  = t & 31;
  const int a2B = (t >> 5) * 2;

  for (int ii = 0; ii < 4; ++ii) {
    const int i = ig * 4 + ii;
    __syncthreads();  // protect s_V/s_w from previous-iter readers (and table init)
    // stage i-slice: s_V[kk*32+o][a2]
    for (int idx = t; idx < 1152; idx += 256) {
      const int kk  = idx >> 7;
      const int rem = idx & 127;
      const int pair = kk * NOc + (rem >> 2);
      const int a4   = (rem & 3) * 4;
      const float4 x = vsite4[(size_t)(kk * NIc + i) * 128 + rem];
      s_V[pair * VSTR + a4 + 0] = x.x;
      s_V[pair * VSTR + a4 + 1] = x.y;
      s_V[pair * VSTR + a4 + 2] = x.z;
      s_V[pair * VSTR + a4 + 3] = x.w;
    }
    __syncthreads();

    // lognum(pair) = base[o] - sum_a2 (V-mu)^2 * i2s
    float ln1, ln2 = -1e30f;
    {
      const int o = t & 31;
      float lp = 0.f;
#pragma unroll
      for (int a2 = 0; a2 < NAc; ++a2) {
        const float d = s_V[t * VSTR + a2] - s_mu[o * VSTR + a2];
        lp = fmaf(d * d, s_is[o * VSTR + a2], lp);
      }
      ln1 = s_base[o] - lp;
    }
    if (t < KOc - 256) {
      const int idx = t + 256;
      const int o = idx & 31;
      float lp = 0.f;
#pragma unroll
      for (int a2 = 0; a2 < NAc; ++a2) {
        const float d = s_V[idx * VSTR + a2] - s_mu[o * VSTR + a2];
        lp = fmaf(d * d, s_is[o * VSTR + a2], lp);
      }
      ln2 = s_base[o] - lp;
    }
    // logsumexp over 288 (kk,o)
    float m = wave_max(fmaxf(ln1, ln2));
    if ((t & 63) == 0) s_red[t >> 6] = m;
    __syncthreads();
    m = fmaxf(fmaxf(s_red[0], s_red[1]), fmaxf(s_red[2], s_red[3]));
    float e = expf(ln1 - m) + ((t < KOc - 256) ? expf(ln2 - m) : 0.f);
    e = wave_sum(e);
    __syncthreads();
    if ((t & 63) == 0) s_red[t >> 6] = e;
    __syncthreads();
    const float logden = m + logf(s_red[0] + s_red[1] + s_red[2] + s_red[3]);

    // w = R2 * act * 0.8
    s_w[t] = expf(ln1 - logden) * s_act[(t >> 5) * NIc + i] * 0.8f;
    if (t < KOc - 256)
      s_w[t + 256] = expf(ln2 - logden) * s_act[8 * NIc + i] * 0.8f;
    __syncthreads();

    if (t < NOc) {
      float sw = 0.f;
#pragma unroll
      for (int kk = 0; kk < KKc; ++kk) sw += s_w[kk * NOc + t];
      sR2acc += sw;
    }
#pragma unroll
    for (int kk = 0; kk < KKc; ++kk) {
      const int bb = kk * NOc + oB;
      const float w  = s_w[bb];
      const float va = s_V[bb * VSTR + a2B];
      const float vb = s_V[bb * VSTR + a2B + 1];
      m2va = fmaf(w, va, m2va);
      m2qa = fmaf(w, va * va, m2qa);
      m2vb = fmaf(w, vb, m2vb);
      m2qb = fmaf(w, vb * vb, m2qb);
    }
  }

  // partials, thread-ordered (K4 uses the same thread mapping)
  reinterpret_cast<float2*>(w_m2v)[(size_t)blockIdx.x * 256 + t] = make_float2(m2va, m2vb);
  reinterpret_cast<float2*>(w_m2q)[(size_t)blockIdx.x * 256 + t] = make_float2(m2qa, m2qb);
  if (t < NOc) w_sR2[(size_t)blockIdx.x * NOc + t] = sR2acc;
}

// ---------------- K4: finalize ----------------
// grid 576; block 256. Thread owns (oB = t&31, a2B = (t>>5)*2) pair — matches K3.
__global__ __launch_bounds__(256)
void em_k4(const float* __restrict__ beta_a, const float* __restrict__ beta_u,
           const float* __restrict__ w_m1v, const float* __restrict__ w_m1q,
           const float* __restrict__ w_sR1,
           const float* __restrict__ w_m2v, const float* __restrict__ w_m2q,
           const float* __restrict__ w_sR2,
           float* __restrict__ out)
{
  const int site = blockIdx.x;
  const int t    = threadIdx.x;
  const int oB   = t & 31;
  const int a2B  = (t >> 5) * 2;

  __shared__ float s_R[NOc];
  __shared__ float s_c[256];

  float Mva = 0.f, Mvb = 0.f, Mqa = 0.f, Mqb = 0.f, sR2 = 0.f;
#pragma unroll
  for (int g = 0; g < 8; ++g) {
    const size_t blk = (size_t)site * 8 + g;
    const float2 v = reinterpret_cast<const float2*>(w_m2v)[blk * 256 + t];
    const float2 q = reinterpret_cast<const float2*>(w_m2q)[blk * 256 + t];
    Mva += v.x; Mvb += v.y; Mqa += q.x; Mqb += q.y;
    if (t < NOc) sR2 += w_sR2[blk * NOc + t];
  }
  if (t < NOc) s_R[t] = sR2;
  __syncthreads();

  const float sumR1 = w_sR1[site];
  const float sumR  = s_R[oB] + 0.2f * sumR1;
  const float sRe   = sumR + EPSf;
  const int p = oB * NAc + a2B;

  Mva += 0.2f * w_m1v[(size_t)site * NPc + p];
  Mqa += 0.2f * w_m1q[(size_t)site * NPc + p];
  Mvb += 0.2f * w_m1v[(size_t)site * NPc + p + 1];
  Mqb += 0.2f * w_m1q[(size_t)site * NPc + p + 1];

  const float mua = Mva / sRe;
  const float mub = Mvb / sRe;
  const float sga = fmaxf((Mqa - mua * mua * (sumR + 2.f * EPSf)) / sRe, 0.f);
  const float sgb = fmaxf((Mqb - mub * mub * (sumR + 2.f * EPSf)) / sRe, 0.f);

  float* poses = out + (size_t)site * NPc;
  poses[p]     = mua;
  poses[p + 1] = mub;

  const float bu = beta_u[oB];
  s_c[t] = (bu - 0.5f * logf(sga + EPSf)) * sumR
         + (bu - 0.5f * logf(sgb + EPSf)) * sumR;
  __syncthreads();
  if (t < NOc) {
    float c = 0.f;
#pragma unroll
    for (int k = 0; k < 8; ++k) c += s_c[t + 32 * k];
    // inv_temp (it_idx=ITERATIONS=2) = 0.01*(1-0.95^3) = 0.00142625
    const float aj = 1.f / (1.f + expf(-(0.00142625f * (beta_a[t] - c))));
    out[(size_t)NSITE * NPc + site * NOc + t] = aj;
  }
}

extern "C" void kernel_launch(void* const* d_in, const int* in_sizes, int n_in,
                              void* d_out, int out_size, void* d_ws, size_t ws_size,
                              hipStream_t stream) {
  const float* votes  = (const float*)d_in[0];
  const float* acts   = (const float*)d_in[1];
  const float* beta_a = (const float*)d_in[2];
  const float* beta_u = (const float*)d_in[3];
  float* out = (float*)d_out;

  // workspace layout (floats); total ~24.3 MB
  float* ws = (float*)d_ws;
  const size_t SP = (size_t)NSITE * NPc;        // 294912
  float* w_mu1  = ws;
  float* w_i2s  = ws + SP;
  float* w_m1v  = ws + 2 * SP;
  float* w_m1q  = ws + 3 * SP;
  float* w_base = ws + 4 * SP;                  // 576*32
  float* w_sR1  = w_base + NSITE * NOc;         // 576 (padded to 1024)
  float* w_m2v  = w_sR1 + 1024;                 // 4608*512
  float* w_m2q  = w_m2v + (size_t)4608 * NPc;
  float* w_sR2  = w_m2q + (size_t)4608 * NPc;   // 4608*32

  em_k1<<<NSITE * 4, 128, 0, stream>>>(votes, acts, beta_a, beta_u,
                                       w_mu1, w_i2s, w_m1v, w_m1q, w_base, w_sR1);
  em_k3<<<NSITE * 8, 256, 0, stream>>>(votes, acts, w_mu1, w_i2s, w_base,
                                       w_m2v, w_m2q, w_sR2);
  em_k4<<<NSITE, 256, 0, stream>>>(beta_a, beta_u, w_m1v, w_m1q, w_sR1,
                                   w_m2v, w_m2q, w_sR2, out);
}

// Round 3
// 554.638 us; speedup vs baseline: 1.0724x; 1.0136x over previous
//
#include <hip/hip_runtime.h>

// EM routing (matrix capsules), B=16,H=6,W=6,KH=KW=3,I=32,O=32,A=4, ITERATIONS=2.
//
// R3: K3 rebuilt around register residency.
//  K1: (site, p-quarter) float4 streaming moments -> mu1/i2s/base/m1 tables.
//  K3: (site, 4-i group). Per i: stage 288x16 slice in natural layout rows
//      padded to 20 dwords (b128 conflict-free), lognum from register tables
//      (mu/i2s loaded once/block), LSE (2 barriers), weights+moments purely in
//      registers; block-end shfl+LDS reduction -> 33x32 partial per block.
//  K4: sum 8 partials/site, 0.2*M1 mix, finalize mu2/sig2/a_j2.
// Fixed harness overhead (ws poison 205us + in restore ~100us) is untouchable;
// our kernels target the 2x votes-pass HBM floor (~115us).

#define KKc 9
#define NIc 32
#define NOc 32
#define NAc 16
#define KIc 288    // KKc*NIc
#define NPc 512    // NOc*NAc
#define NSITE 576
#define RSTR 20    // padded dword stride for V rows (16 data + 4 pad)

#define EPSf 1e-7f
#define TWO_PIf 6.28318530717958647692f

__device__ __forceinline__ float wave_sum(float v) {
#pragma unroll
  for (int off = 32; off; off >>= 1) v += __shfl_down(v, off, 64);
  return v;
}
__device__ __forceinline__ float wave_max(float v) {
#pragma unroll
  for (int off = 32; off; off >>= 1) v = fmaxf(v, __shfl_down(v, off, 64));
  return v;
}

// ---------------- K1: M-step-1 ----------------
// grid 2304 = site*4+qtr; block 128. Thread owns float4 col c = qtr*32+(t&31),
// rows ki = (t>>5) + 4k. Cross-row fold: shfl_xor(32) then 1 LDS hop.
__global__ __launch_bounds__(128)
void em_k1(const float* __restrict__ votes, const float* __restrict__ acts_in,
           const float* __restrict__ beta_a, const float* __restrict__ beta_u,
           float* __restrict__ w_mu1, float* __restrict__ w_i2s,
           float* __restrict__ w_m1v, float* __restrict__ w_m1q,
           float* __restrict__ w_base, float* __restrict__ w_sR1)
{
  const int site = blockIdx.x >> 2;
  const int qtr  = blockIdx.x & 3;
  const int t    = threadIdx.x;

  __shared__ float s_act[KIc];
  __shared__ float s_red[2];
  __shared__ float s_cr[32 * 9];

  s_act[t] = acts_in[site * KIc + t];
  s_act[t + 128] = acts_in[site * KIc + t + 128];
  if (t < 32) s_act[t + 256] = acts_in[site * KIc + t + 256];
  __syncthreads();

  float v = fmaf(0.8f, s_act[t], 0.2f) + fmaf(0.8f, s_act[t + 128], 0.2f);
  if (t < 32) v += fmaf(0.8f, s_act[t + 256], 0.2f);
  v = wave_sum(v);
  if ((t & 63) == 0) s_red[t >> 6] = v;
  __syncthreads();
  const float sumR1 = (s_red[0] + s_red[1]) * 0.03125f;

  const int c  = qtr * 32 + (t & 31);   // float4 column 0..127
  const int r0 = t >> 5;                // 0..3
  float pv0 = 0.f, pv1 = 0.f, pv2 = 0.f, pv3 = 0.f;
  float pq0 = 0.f, pq1 = 0.f, pq2 = 0.f, pq3 = 0.f;
  const float4* vb = reinterpret_cast<const float4*>(votes) + (size_t)site * (KIc * 128) + c;
#pragma unroll 8
  for (int k = 0; k < 72; ++k) {
    const int ki = r0 + 4 * k;
    const float r = fmaf(0.8f, s_act[ki], 0.2f) * 0.03125f;
    const float4 x = vb[(size_t)ki * 128];
    pv0 = fmaf(r, x.x, pv0); pq0 = fmaf(r, x.x * x.x, pq0);
    pv1 = fmaf(r, x.y, pv1); pq1 = fmaf(r, x.y * x.y, pq1);
    pv2 = fmaf(r, x.z, pv2); pq2 = fmaf(r, x.z * x.z, pq2);
    pv3 = fmaf(r, x.w, pv3); pq3 = fmaf(r, x.w * x.w, pq3);
  }
  // fold rows r0 pairs within wave
  pv0 += __shfl_xor(pv0, 32); pv1 += __shfl_xor(pv1, 32);
  pv2 += __shfl_xor(pv2, 32); pv3 += __shfl_xor(pv3, 32);
  pq0 += __shfl_xor(pq0, 32); pq1 += __shfl_xor(pq1, 32);
  pq2 += __shfl_xor(pq2, 32); pq3 += __shfl_xor(pq3, 32);
  if (t >= 64 && t < 96) {
    const int l = t - 64;
    s_cr[l * 9 + 0] = pv0; s_cr[l * 9 + 1] = pv1; s_cr[l * 9 + 2] = pv2; s_cr[l * 9 + 3] = pv3;
    s_cr[l * 9 + 4] = pq0; s_cr[l * 9 + 5] = pq1; s_cr[l * 9 + 6] = pq2; s_cr[l * 9 + 7] = pq3;
  }
  __syncthreads();
  if (t < 32) {
    pv0 += s_cr[t * 9 + 0]; pv1 += s_cr[t * 9 + 1]; pv2 += s_cr[t * 9 + 2]; pv3 += s_cr[t * 9 + 3];
    pq0 += s_cr[t * 9 + 4]; pq1 += s_cr[t * 9 + 5]; pq2 += s_cr[t * 9 + 6]; pq3 += s_cr[t * 9 + 7];

    const float sR1e = sumR1 + EPSf;
    const float sR1x = sumR1 + 2.f * EPSf;
    const float mu0 = pv0 / sR1e, mu1 = pv1 / sR1e, mu2 = pv2 / sR1e, mu3 = pv3 / sR1e;
    const float sg0 = fmaxf((pq0 - mu0 * mu0 * sR1x) / sR1e, 0.f);
    const float sg1 = fmaxf((pq1 - mu1 * mu1 * sR1x) / sR1e, 0.f);
    const float sg2 = fmaxf((pq2 - mu2 * mu2 * sR1x) / sR1e, 0.f);
    const float sg3 = fmaxf((pq3 - mu3 * mu3 * sR1x) / sR1e, 0.f);

    const size_t fo = (size_t)site * 128 + c;
    reinterpret_cast<float4*>(w_mu1)[fo] = make_float4(mu0, mu1, mu2, mu3);
    reinterpret_cast<float4*>(w_i2s)[fo] = make_float4(0.5f / sg0, 0.5f / sg1, 0.5f / sg2, 0.5f / sg3);
    reinterpret_cast<float4*>(w_m1v)[fo] = make_float4(pv0, pv1, pv2, pv3);
    reinterpret_cast<float4*>(w_m1q)[fo] = make_float4(pq0, pq1, pq2, pq3);

    const int o = c >> 2;
    const float bu = beta_u[o];
    float lt = logf(TWO_PIf * sg0 + EPSf) + logf(TWO_PIf * sg1 + EPSf)
             + logf(TWO_PIf * sg2 + EPSf) + logf(TWO_PIf * sg3 + EPSf);
    float ch = (4.f * bu - 0.5f * (logf(sg0 + EPSf) + logf(sg1 + EPSf)
                                 + logf(sg2 + EPSf) + logf(sg3 + EPSf))) * sumR1;
    ch += __shfl_xor(ch, 1); ch += __shfl_xor(ch, 2);
    lt += __shfl_xor(lt, 1); lt += __shfl_xor(lt, 2);
    if ((t & 3) == 0) {
      // inv_temp (it=0) = 0.01*(1-0.95) = 0.0005
      const float aj = 1.f / (1.f + expf(-(0.0005f * (beta_a[o] - ch))));
      w_base[site * NOc + o] = logf(aj + EPSf) - lt;
    }
    if (t == 0) w_sR1[site] = sumR1;
  }
}

// ---------------- K3: E-step + M-step-2 partials ----------------
// grid 4608; block 256. site reversed for L3 reuse of K1's tail.
__global__ __launch_bounds__(256)
void em_k3(const float* __restrict__ votes, const float* __restrict__ acts_in,
           const float* __restrict__ w_mu1, const float* __restrict__ w_i2s,
           const float* __restrict__ w_base, float* __restrict__ w_part)
{
  const int site = (NSITE - 1) - (blockIdx.x >> 3);
  const int ig   = blockIdx.x & 7;
  const int t    = threadIdx.x;
  const int o    = t & 31;

  __shared__ float s_V[288 * RSTR];   // 23040B; also aliased as s_p[33*128] at end
  __shared__ float s_act[KIc];
  __shared__ float s_base[NOc];
  __shared__ float s_rm[4];
  __shared__ float s_re[4];

  // ---- bounce tables through s_V (stride 17 region) into registers ----
  {
    const int tt = t & 127;
    const float4 x = reinterpret_cast<const float4*>((t < 128 ? w_mu1 : w_i2s) + (size_t)site * NPc)[tt];
    float* dst = s_V + (t < 128 ? 0 : 544) + (tt >> 2) * 17 + (tt & 3) * 4;
    dst[0] = x.x; dst[1] = x.y; dst[2] = x.z; dst[3] = x.w;
  }
  s_act[t] = acts_in[site * KIc + t];
  if (t < 32) { s_act[256 + t] = acts_in[site * KIc + 256 + t]; s_base[t] = w_base[site * NOc + t]; }
  __syncthreads();
  float mu[16], is[16];
#pragma unroll
  for (int a = 0; a < 16; ++a) { mu[a] = s_V[o * 17 + a]; is[a] = s_V[544 + o * 17 + a]; }
  const float lbase = s_base[o];
  __syncthreads();  // table reads done before first staging overwrite

  float accv[16], accq[16], accw = 0.f;
#pragma unroll
  for (int a = 0; a < 16; ++a) { accv[a] = 0.f; accq[a] = 0.f; }

  const float4* vsl4 = reinterpret_cast<const float4*>(votes) + (size_t)site * (KIc * 128);

  for (int ii = 0; ii < 4; ++ii) {
    const int i = ig * 4 + ii;
    // stage i-slice, natural layout rows of 16 + 4 pad dwords
#pragma unroll
    for (int idx = t; idx < 1152; idx += 256) {
      const int row = idx >> 2;          // kk*32 + o2
      const int a4  = idx & 3;
      const float4 x = vsl4[(size_t)((row >> 5) * NIc + i) * 128 + (row & 31) * 4 + a4];
      *reinterpret_cast<float4*>(s_V + row * RSTR + a4 * 4) = x;
    }
    __syncthreads();

    // lognum for row t (all) and row 256+t (t<32)
    float v1[16];
#pragma unroll
    for (int j = 0; j < 4; ++j) {
      const float4 x = *reinterpret_cast<const float4*>(s_V + t * RSTR + 4 * j);
      v1[4 * j] = x.x; v1[4 * j + 1] = x.y; v1[4 * j + 2] = x.z; v1[4 * j + 3] = x.w;
    }
    float lp1 = 0.f;
#pragma unroll
    for (int a = 0; a < 16; ++a) { const float d = v1[a] - mu[a]; lp1 = fmaf(d * d, is[a], lp1); }
    const float ln1 = lbase - lp1;

    float v2[16];
    float ln2 = -1e30f;
    if (t < 32) {
#pragma unroll
      for (int j = 0; j < 4; ++j) {
        const float4 x = *reinterpret_cast<const float4*>(s_V + (256 + t) * RSTR + 4 * j);
        v2[4 * j] = x.x; v2[4 * j + 1] = x.y; v2[4 * j + 2] = x.z; v2[4 * j + 3] = x.w;
      }
      float lp2 = 0.f;
#pragma unroll
      for (int a = 0; a < 16; ++a) { const float d = v2[a] - mu[a]; lp2 = fmaf(d * d, is[a], lp2); }
      ln2 = lbase - lp2;
    }

    // logsumexp over 288 rows
    float m = wave_max(fmaxf(ln1, ln2));
    if ((t & 63) == 0) s_rm[t >> 6] = m;
    __syncthreads();
    m = fmaxf(fmaxf(s_rm[0], s_rm[1]), fmaxf(s_rm[2], s_rm[3]));
    float e = expf(ln1 - m) + ((t < 32) ? expf(ln2 - m) : 0.f);
    e = wave_sum(e);
    if ((t & 63) == 0) s_re[t >> 6] = e;
    __syncthreads();
    const float logden = m + logf(s_re[0] + s_re[1] + s_re[2] + s_re[3]);

    // weights + moment accumulation, all registers
    const float w1 = expf(ln1 - logden) * s_act[(t >> 5) * NIc + i] * 0.8f;
    accw += w1;
#pragma unroll
    for (int a = 0; a < 16; ++a) {
      accv[a] = fmaf(w1, v1[a], accv[a]);
      accq[a] = fmaf(w1, v1[a] * v1[a], accq[a]);
    }
    if (t < 32) {
      const float w2 = expf(ln2 - logden) * s_act[8 * NIc + i] * 0.8f;
      accw += w2;
#pragma unroll
      for (int a = 0; a < 16; ++a) {
        accv[a] = fmaf(w2, v2[a], accv[a]);
        accq[a] = fmaf(w2, v2[a] * v2[a], accq[a]);
      }
    }
    // next staging is safe: all s_V reads precede the max-barrier above
  }

  // ---- block reduction over kk: shfl fold + 4-wave LDS combine ----
  accw += __shfl_xor(accw, 32);
#pragma unroll
  for (int a = 0; a < 16; ++a) {
    accv[a] += __shfl_xor(accv[a], 32);
    accq[a] += __shfl_xor(accq[a], 32);
  }
  float* s_p = s_V;   // 33*128 = 4224 <= 5760
  {
    const int l = t & 63, wv = t >> 6;
    if (l < 32) {
#pragma unroll
      for (int a = 0; a < 16; ++a) {
        s_p[a * 128 + wv * 32 + l] = accv[a];
        s_p[(16 + a) * 128 + wv * 32 + l] = accq[a];
      }
      s_p[32 * 128 + wv * 32 + l] = accw;
    }
  }
  __syncthreads();
  float* wp = w_part + (size_t)(site * 8 + ig) * (33 * 32);
  for (int j = t >> 5; j < 33; j += 8) {
    const float s = s_p[j * 128 + o] + s_p[j * 128 + 32 + o]
                  + s_p[j * 128 + 64 + o] + s_p[j * 128 + 96 + o];
    wp[j * 32 + o] = s;
  }
}

// ---------------- K4: finalize ----------------
__global__ __launch_bounds__(256)
void em_k4(const float* __restrict__ beta_a, const float* __restrict__ beta_u,
           const float* __restrict__ w_m1v, const float* __restrict__ w_m1q,
           const float* __restrict__ w_sR1, const float* __restrict__ w_part,
           float* __restrict__ out)
{
  const int site = blockIdx.x;
  const int t    = threadIdx.x;
  const int oB   = t & 31;
  const int a2B  = (t >> 5) * 2;

  __shared__ float s_M[33 * 32];
  __shared__ float s_c[256];

  for (int j = t >> 5; j < 33; j += 8) {
    float s = 0.f;
#pragma unroll
    for (int g = 0; g < 8; ++g)
      s += w_part[(size_t)(site * 8 + g) * (33 * 32) + j * 32 + oB];
    s_M[j * 32 + oB] = s;
  }
  __syncthreads();

  const float sumR1 = w_sR1[site];
  const float sumR  = s_M[32 * 32 + oB] + 0.2f * sumR1;
  const float sRe   = sumR + EPSf;
  const float sRx   = sumR + 2.f * EPSf;
  const int p = oB * NAc + a2B;

  const float Mva = s_M[a2B * 32 + oB]        + 0.2f * w_m1v[(size_t)site * NPc + p];
  const float Mvb = s_M[(a2B + 1) * 32 + oB]  + 0.2f * w_m1v[(size_t)site * NPc + p + 1];
  const float Mqa = s_M[(16 + a2B) * 32 + oB] + 0.2f * w_m1q[(size_t)site * NPc + p];
  const float Mqb = s_M[(17 + a2B) * 32 + oB] + 0.2f * w_m1q[(size_t)site * NPc + p + 1];

  const float mua = Mva / sRe;
  const float mub = Mvb / sRe;
  const float sga = fmaxf((Mqa - mua * mua * sRx) / sRe, 0.f);
  const float sgb = fmaxf((Mqb - mub * mub * sRx) / sRe, 0.f);

  reinterpret_cast<float2*>(out + (size_t)site * NPc)[p >> 1] = make_float2(mua, mub);

  const float bu = beta_u[oB];
  s_c[t] = (bu - 0.5f * logf(sga + EPSf)) * sumR
         + (bu - 0.5f * logf(sgb + EPSf)) * sumR;
  __syncthreads();
  if (t < NOc) {
    float c = 0.f;
#pragma unroll
    for (int k = 0; k < 8; ++k) c += s_c[t + 32 * k];
    // inv_temp (it_idx=ITERATIONS=2) = 0.01*(1-0.95^3) = 0.00142625
    const float aj = 1.f / (1.f + expf(-(0.00142625f * (beta_a[t] - c))));
    out[(size_t)NSITE * NPc + site * NOc + t] = aj;
  }
}

extern "C" void kernel_launch(void* const* d_in, const int* in_sizes, int n_in,
                              void* d_out, int out_size, void* d_ws, size_t ws_size,
                              hipStream_t stream) {
  const float* votes  = (const float*)d_in[0];
  const float* acts   = (const float*)d_in[1];
  const float* beta_a = (const float*)d_in[2];
  const float* beta_u = (const float*)d_in[3];
  float* out = (float*)d_out;

  float* ws = (float*)d_ws;
  const size_t SP = (size_t)NSITE * NPc;        // 294912
  float* w_mu1  = ws;
  float* w_i2s  = ws + SP;
  float* w_m1v  = ws + 2 * SP;
  float* w_m1q  = ws + 3 * SP;
  float* w_base = ws + 4 * SP;                  // 576*32
  float* w_sR1  = w_base + NSITE * NOc;         // 576 (padded to 1024)
  float* w_part = w_sR1 + 1024;                 // 4608*33*32 floats (~19.5MB)

  em_k1<<<NSITE * 4, 128, 0, stream>>>(votes, acts, beta_a, beta_u,
                                       w_mu1, w_i2s, w_m1v, w_m1q, w_base, w_sR1);
  em_k3<<<NSITE * 8, 256, 0, stream>>>(votes, acts, w_mu1, w_i2s, w_base, w_part);
  em_k4<<<NSITE, 256, 0, stream>>>(beta_a, beta_u, w_m1v, w_m1q, w_sR1, w_part, out);
}